// Round 3
// baseline (106.096 us; speedup 1.0000x reference)
//
#include <hip/hip_runtime.h>
#include <hip/hip_bf16.h>

// B=32, D=128, H=256, O=10.
// s = 1-tanh(W1^T x + b1)^2, u = -2 z s, P = W1^T W1 (HxH).
// Rank-10 structure (M = W2 W2^T):
//   sw2[g,o] = s_g W2[g,o]; F1 = W1 sw2 (128x10); E = W1^T F1 (256x10)
//   y_o = sum_h W2[h,o] u_h w_h^2  (w = W1^T v)
//   a_un = W1 (s o (W2 y)) = F1 y
//   C[o,p] = sum_g sw2[g,o] E[g,p] (10x10), CW = C W2^T
//   F^2 = 2 sum u_h u_h' (P^2 o Q + P o R o R^T)
//   a_i = -a_un[i]/((F+1e-6)(||v||+1e-6))
// FUSED single launch: blocks 0..31 = batch pipeline (everything in LDS/regs),
// blocks 32..287 = one P row each. One-way dependency (batch needs full P)
// via device-scope flag g_pdone: helpers release-add after L2 writeback; batch
// blocks acquire-spin then L2-invalidate. Only 32 blocks ever spin => 256
// helpers always have free CUs => deadlock-free by geometry. Flags self-reset
// (last batch block) => no init kernel, graph-replay safe.

#define NB 32

// workspace float offsets: only P remains in global
#define OP    0        // 65536 floats: P [h*256+g]

__device__ int g_pdone = 0;
__device__ int g_bdone = 0;

template<int BF> __device__ __forceinline__ float ld(const void* p, int i) {
  if constexpr (BF) return __bfloat162float(((const __hip_bfloat16*)p)[i]);
  else return ((const float*)p)[i];
}
template<int BF> __device__ __forceinline__ void st(void* p, int i, float v) {
  if constexpr (BF) ((__hip_bfloat16*)p)[i] = __float2bfloat16(v);
  else ((float*)p)[i] = v;
}
__device__ __forceinline__ float b2f(unsigned short u) {
  return __uint_as_float(((unsigned int)u) << 16);
}
// 8 consecutive elements, idx %4==0 (BF path: one 16B uint4 load)
template<int BF> __device__ __forceinline__ void ld8v(const void* p, int i, float* o) {
  if constexpr (BF) {
    uint4 u = *(const uint4*)((const unsigned short*)p + i);
    o[0] = b2f((unsigned short)(u.x & 0xffff)); o[1] = b2f((unsigned short)(u.x >> 16));
    o[2] = b2f((unsigned short)(u.y & 0xffff)); o[3] = b2f((unsigned short)(u.y >> 16));
    o[4] = b2f((unsigned short)(u.z & 0xffff)); o[5] = b2f((unsigned short)(u.z >> 16));
    o[6] = b2f((unsigned short)(u.w & 0xffff)); o[7] = b2f((unsigned short)(u.w >> 16));
  } else {
    float4 a = *(const float4*)((const float*)p + i);
    float4 b = *(const float4*)((const float*)p + i + 4);
    o[0]=a.x; o[1]=a.y; o[2]=a.z; o[3]=a.w; o[4]=b.x; o[5]=b.y; o[6]=b.z; o[7]=b.w;
  }
}

// dtype sniff: view first 256 half-words of state_batch as bf16. fp32 storage
// puts random-exponent garbage in the low halves -> some |v|>1000 w.p. ~1.
__device__ __forceinline__ int blocksniff(const void* sb, int* sh) {
  if (threadIdx.x == 0) *sh = 0;
  __syncthreads();
  float v = fabsf(__bfloat162float(((const __hip_bfloat16*)sb)[threadIdx.x & 255]));
  if (!(v < 1000.0f)) atomicOr(sh, 1);
  __syncthreads();
  return (*sh == 0) ? 1 : 0;
}

// LDS carve (floats) for batch path
#define LXS   0       // 128
#define LVS   128     // 128
#define LW2   256     // 2560 (raw W2, stride 10)
#define LYS   2816    // 16: [0..9]=y, [10]=||v||
#define LRED  2832    // 48: wave partials, reused for F^2 reduce
#define LF1   2880    // 128*12
#define LEL   4416    // 256*12: [0..9]=E, [10]=u
#define LSW2  7488    // 256*12
#define LCL   10560   // 100
#define LCL2  10660   // 100
#define LW2P  10760   // 256*12 padded W2
#define LTOT  13832   // 55.3 KB -> 2 blocks/CU

#define F1ACC(wv, gidx) do { \
    const float* sp_ = &sm[LSW2 + (gidx)*12]; \
    float4 s0_ = *(const float4*)sp_; \
    float4 s1_ = *(const float4*)(sp_+4); \
    float2 s2_ = *(const float2*)(sp_+8); \
    fa[0]+=(wv)*s0_.x; fa[1]+=(wv)*s0_.y; fa[2]+=(wv)*s0_.z; fa[3]+=(wv)*s0_.w; \
    fa[4]+=(wv)*s1_.x; fa[5]+=(wv)*s1_.y; fa[6]+=(wv)*s1_.z; fa[7]+=(wv)*s1_.w; \
    fa[8]+=(wv)*s2_.x; fa[9]+=(wv)*s2_.y; \
  } while (0)

template<int BF>
__device__ void fk_body(const void* tin, const void* sbin, const void* x0in,
                        const void* x1in, const void* W1in, const void* b1in,
                        const void* W2in, void* out, float* ws, float* sm) {
  int bid = blockIdx.x, t = threadIdx.x;
  if (bid >= NB) {
    // ---- helper block: P row (row = bid-NB) ----
    int row = bid - NB;
    float* colh = sm;            // 128
    if (t < 128) colh[t] = ld<BF>(W1in, t * 256 + row);
    __syncthreads();
    float pacc = 0.f;
    for (int d = 0; d < 128; d += 4) {
      float4 c4 = *(const float4*)&colh[d];
      pacc += c4.x * ld<BF>(W1in, (d + 0) * 256 + t);
      pacc += c4.y * ld<BF>(W1in, (d + 1) * 256 + t);
      pacc += c4.z * ld<BF>(W1in, (d + 2) * 256 + t);
      pacc += c4.w * ld<BF>(W1in, (d + 3) * 256 + t);
    }
    ws[OP + row * 256 + t] = pacc;
    __syncthreads();   // drains vmcnt: all 256 stores complete (in L2)
    if (t == 0) {
      __threadfence(); // agent-scope release: L2 writeback
      __hip_atomic_fetch_add(&g_pdone, 1, __ATOMIC_RELEASE, __HIP_MEMORY_SCOPE_AGENT);
    }
    return;
  }
  // ---- batch block b ----
  int b = bid;
  int w = t >> 6;
  float tt = ld<BF>(tin, 0);
  float window = 4.f * tt * (1.f - tt);
  if (t < 128) {
    float dev = ld<BF>(sbin, b * 128 + t);
    float v   = ld<BF>(sbin, (NB + b) * 128 + t);
    float x0v = ld<BF>(x0in, b * 128 + t);
    float x1v = ld<BF>(x1in, b * 128 + t);
    sm[LXS + t] = x0v + tt * (x1v - x0v) + window * dev;
    sm[LVS + t] = v;
  }
  for (int i = t; i < 2560; i += 256) sm[LW2 + i] = ld<BF>(W2in, i);
  __syncthreads();                                   // (1)
  // h, w projections (coalesced column reads)
  float hacc = ld<BF>(b1in, t), wacc = 0.f;
  for (int d = 0; d < 128; d += 4) {
    float4 xv = *(const float4*)&sm[LXS + d];
    float4 vv = *(const float4*)&sm[LVS + d];
    float w0 = ld<BF>(W1in, (d + 0) * 256 + t);
    float w1 = ld<BF>(W1in, (d + 1) * 256 + t);
    float w2 = ld<BF>(W1in, (d + 2) * 256 + t);
    float w3 = ld<BF>(W1in, (d + 3) * 256 + t);
    hacc += w0 * xv.x + w1 * xv.y + w2 * xv.z + w3 * xv.w;
    wacc += w0 * vv.x + w1 * vv.y + w2 * vv.z + w3 * vv.w;
  }
  float z  = tanhf(hacc);
  float sg = 1.f - z * z;
  float ug = -2.f * z * sg;
  // own W2 row to regs; sw2 row; padded W2 copy for F^2 phase
  float w2r[10];
  #pragma unroll
  for (int o = 0; o < 10; ++o) w2r[o] = sm[LW2 + t * 10 + o];
  #pragma unroll
  for (int o = 0; o < 10; ++o) sm[LSW2 + t * 12 + o] = sg * w2r[o];
  for (int i = t; i < 3072; i += 256) {
    int r = i / 12, c = i - r * 12;
    sm[LW2P + i] = (c < 10) ? sm[LW2 + r * 10 + c] : 0.f;
  }
  // wave-parallel reductions: y[0..9] and ||v||^2 (slot 10)
  float cval = ug * wacc * wacc;
  float rv[11];
  #pragma unroll
  for (int o = 0; o < 10; ++o) rv[o] = cval * w2r[o];
  rv[10] = (t < 128) ? sm[LVS + t] * sm[LVS + t] : 0.f;
  #pragma unroll
  for (int o = 0; o < 11; ++o) {
    float v = rv[o];
    #pragma unroll
    for (int m = 32; m > 0; m >>= 1) v += __shfl_xor(v, m);
    if ((t & 63) == 0) sm[LRED + w * 12 + o] = v;
  }
  __syncthreads();                                   // (2) sw2/W2P/LRED ready
  if (t < 11) {
    float s = sm[LRED + t] + sm[LRED + 12 + t] + sm[LRED + 24 + t] + sm[LRED + 36 + t];
    if (t < 10) sm[LYS + t] = s;
    else        sm[LYS + 10] = sqrtf(s);             // ||v|| stays in LDS
  }
  // F1[r,o] = sum_g W1[r,g] sw2[g,o]; each thread does half the g-range of one row
  int half = t >> 7, r = t & 127;
  float fa[10];
  #pragma unroll
  for (int o = 0; o < 10; ++o) fa[o] = 0.f;
  {
    const int gbase = half * 128;
    for (int gg = 0; gg < 128; gg += 8) {
      int g = gbase + gg;
      float wv[8];
      ld8v<BF>(W1in, r * 256 + g, wv);   // 16B row gather
      F1ACC(wv[0], g + 0); F1ACC(wv[1], g + 1);
      F1ACC(wv[2], g + 2); F1ACC(wv[3], g + 3);
      F1ACC(wv[4], g + 4); F1ACC(wv[5], g + 5);
      F1ACC(wv[6], g + 6); F1ACC(wv[7], g + 7);
    }
  }
  if (half) {
    #pragma unroll
    for (int o = 0; o < 10; ++o) sm[LF1 + r * 12 + o] = fa[o];
  }
  __syncthreads();                                   // (3) upper partials in LDS
  float aun = 0.f;
  if (!half) {   // t < 128: finalize F1 row, a_un = F1 . y (kept in reg)
    #pragma unroll
    for (int o = 0; o < 10; ++o) {
      float f = fa[o] + sm[LF1 + r * 12 + o];
      sm[LF1 + r * 12 + o] = f;
      aun += f * sm[LYS + o];
    }
  }
  __syncthreads();                                   // (4) F1 final
  // E[t,o] = sum_d W1[d,t] F1[d,o]  (coalesced column reads, broadcast LDS)
  float er[10];
  #pragma unroll
  for (int o = 0; o < 10; ++o) er[o] = 0.f;
  for (int d = 0; d < 128; ++d) {
    float w1v = ld<BF>(W1in, d * 256 + t);
    const float* fp = &sm[LF1 + d * 12];
    float4 a0 = *(const float4*)fp;
    float4 a1 = *(const float4*)(fp + 4);
    float2 a2 = *(const float2*)(fp + 8);
    er[0] += w1v * a0.x; er[1] += w1v * a0.y; er[2] += w1v * a0.z; er[3] += w1v * a0.w;
    er[4] += w1v * a1.x; er[5] += w1v * a1.y; er[6] += w1v * a1.z; er[7] += w1v * a1.w;
    er[8] += w1v * a2.x; er[9] += w1v * a2.y;
  }
  #pragma unroll
  for (int o = 0; o < 10; ++o) sm[LEL + t * 12 + o] = er[o];
  sm[LEL + t * 12 + 10] = ug;                        // u in slot 10
  sm[LEL + t * 12 + 11] = 0.f;
  __syncthreads();                                   // (5) E+u in LDS
  // C[o,p] = sum_g sw2[g,o] E[g,p] -- 200 threads, split g-range
  float cpart = 0.f;
  if (t < 200) {
    int gh = (t >= 100) ? 1 : 0;
    int idx = t - gh * 100;
    int o = idx / 10, p = idx - o * 10;
    const float* sa = &sm[LSW2 + gh * 1536 + o];
    const float* sb = &sm[LEL  + gh * 1536 + p];
    #pragma unroll 4
    for (int g = 0; g < 128; ++g) cpart += sa[g * 12] * sb[g * 12];
    if (gh) sm[LCL2 + idx] = cpart;
  }
  __syncthreads();                                   // (6)
  if (t < 100) sm[LCL + t] = cpart + sm[LCL2 + t];
  __syncthreads();                                   // (7)
  // CW row for this thread's h' -> registers (no global round trip)
  float cwr[10];
  #pragma unroll
  for (int o = 0; o < 10; ++o) {
    float cw = 0.f;
    #pragma unroll
    for (int p = 0; p < 10; ++p) cw += sm[LCL + o * 10 + p] * w2r[p];
    cwr[o] = cw;
  }
  // ---- wait for P (helpers are long done by now in the common case) ----
  if (t == 0) {
    while (__hip_atomic_load(&g_pdone, __ATOMIC_ACQUIRE, __HIP_MEMORY_SCOPE_AGENT) < 256)
      __builtin_amdgcn_s_sleep(2);
  }
  __syncthreads();                                   // (8)
  __threadfence();   // agent acquire: invalidate L2 so P reads are fresh
  // ---- F^2 accumulation ----
  float acc = 0.f;
  for (int i0 = 0; i0 < 64; i0 += 8) {
    float ph[8];
    #pragma unroll
    for (int j = 0; j < 8; ++j)
      ph[j] = ws[OP + (w * 64 + i0 + j) * 256 + t];   // 8 L2 loads in flight
    #pragma unroll
    for (int j = 0; j < 8; ++j) {
      int h = w * 64 + i0 + j;
      const float* rp = &sm[LEL + h * 12];
      float4 E0 = *(const float4*)rp;
      float4 E1 = *(const float4*)(rp + 4);
      float4 E2 = *(const float4*)(rp + 8);     // E8,E9,u,0
      const float* wp = &sm[LW2P + h * 12];
      float4 W0 = *(const float4*)wp;
      float4 W1v = *(const float4*)(wp + 4);
      float4 W2v = *(const float4*)(wp + 8);    // W8,W9,0,0
      float R = E0.x*w2r[0] + E0.y*w2r[1] + E0.z*w2r[2] + E0.w*w2r[3]
              + E1.x*w2r[4] + E1.y*w2r[5] + E1.z*w2r[6] + E1.w*w2r[7]
              + E2.x*w2r[8] + E2.y*w2r[9];
      float Rt = W0.x*er[0] + W0.y*er[1] + W0.z*er[2] + W0.w*er[3]
               + W1v.x*er[4] + W1v.y*er[5] + W1v.z*er[6] + W1v.w*er[7]
               + W2v.x*er[8] + W2v.y*er[9];
      float Qd = W0.x*cwr[0] + W0.y*cwr[1] + W0.z*cwr[2] + W0.w*cwr[3]
               + W1v.x*cwr[4] + W1v.y*cwr[5] + W1v.z*cwr[6] + W1v.w*cwr[7]
               + W2v.x*cwr[8] + W2v.y*cwr[9];
      acc += E2.z * ph[j] * (ph[j] * Qd + R * Rt);
    }
  }
  acc *= ug;           // u for own column t
  #pragma unroll
  for (int m = 32; m > 0; m >>= 1) acc += __shfl_xor(acc, m);
  if ((t & 63) == 0) sm[LRED + w] = acc;             // LRED reused (old use dead)
  __syncthreads();                                   // (9)
  float F = sqrtf(fmaxf(2.f * (sm[LRED] + sm[LRED+1] + sm[LRED+2] + sm[LRED+3]), 0.f));
  float denom = (F + 1e-6f) * (sm[LYS + 10] + 1e-6f);
  if (t < 128) {
    st<BF>(out, b * 128 + t, ld<BF>(sbin, (NB + b) * 128 + t));   // dev_velocity
    float dev = ld<BF>(sbin, b * 128 + t);
    float val = -aun / denom - 0.1f * dev;
    st<BF>(out, (NB + b) * 128 + t, val);
  }
  __syncthreads();                                   // (10)
  if (t == 0) {
    int old = __hip_atomic_fetch_add(&g_bdone, 1, __ATOMIC_ACQ_REL, __HIP_MEMORY_SCOPE_AGENT);
    if (old == NB - 1) {   // last batch block: reset flags for next launch
      __hip_atomic_store(&g_pdone, 0, __ATOMIC_RELAXED, __HIP_MEMORY_SCOPE_AGENT);
      __hip_atomic_store(&g_bdone, 0, __ATOMIC_RELAXED, __HIP_MEMORY_SCOPE_AGENT);
    }
  }
}

__global__ __launch_bounds__(256, 2) void FK(const void* tin, const void* sbin,
                                             const void* x0in, const void* x1in,
                                             const void* W1in, const void* b1in,
                                             const void* W2in, void* out, float* ws) {
  __shared__ int sh;
  __shared__ __align__(16) float sm[LTOT];
  int bf = blocksniff(sbin, &sh);
  if (bf) fk_body<1>(tin, sbin, x0in, x1in, W1in, b1in, W2in, out, ws, sm);
  else    fk_body<0>(tin, sbin, x0in, x1in, W1in, b1in, W2in, out, ws, sm);
}

extern "C" void kernel_launch(void* const* d_in, const int* in_sizes, int n_in,
                              void* d_out, int out_size, void* d_ws, size_t ws_size,
                              hipStream_t stream) {
  float* ws = (float*)d_ws;
  const void* tin  = d_in[0];
  const void* sbin = d_in[1];
  const void* x0in = d_in[2];
  const void* x1in = d_in[3];
  const void* W1in = d_in[4];
  const void* b1in = d_in[5];
  const void* W2in = d_in[6];
  // d_in[7] (b2) cancels in every derivative.

  FK<<<dim3(NB + 256), dim3(256), 0, stream>>>(tin, sbin, x0in, x1in, W1in, b1in, W2in, d_out, ws);
}

// Round 4
// 99.539 us; speedup vs baseline: 1.0659x; 1.0659x over previous
//
#include <hip/hip_runtime.h>
#include <hip/hip_bf16.h>

// B=32, D=128, H=256, O=10.
// s = 1-tanh(W1^T x + b1)^2, u = -2 z s, P = W1^T W1 (HxH).
// Rank-10 structure (M = W2 W2^T):
//   sw2[g,o] = s_g W2[g,o]; F1 = W1 sw2 (128x10); E = W1^T F1 (256x10)
//   y_o = sum_h W2[h,o] u_h w_h^2  (w = W1^T v)
//   a_un = W1 (s o (W2 y)) = F1 y
//   C[o,p] = sum_g sw2[g,o] E[g,p] (10x10), CW = C W2^T
//   F^2 = 2 sum u_h u_h' (P^2 o Q + P o R o R^T)
//   a_i = -a_un[i]/((F+1e-6)(||v||+1e-6))
// FUSED single launch, FENCE-FREE handoff (round-3 post-mortem: __threadfence /
// RELEASE-acquire at agent scope emit buffer_wbl2/buffer_inv on gfx950 -> L2
// maintenance storm, 40us idle). Now: helpers write P with RELAXED agent
// atomic stores (sc1, straight to coherent point, no dirty L2 lines); flag is
// RELAXED agent fetch_add after __syncthreads (vmcnt(0) drain = physical
// ordering); consumers spin on RELAXED agent load (no buffer_inv) and read P
// with plain loads (no stale copies can exist: kernel-start acquire
// invalidated L2s, sc1 stores never allocate dirty lines, first touch is
// after the flag). Deadlock-free by geometry: only 32 blocks spin, 256
// helpers always have free CUs. Flags self-reset (last batch block).

#define NB 32

// workspace float offsets: only P remains in global
#define OP    0        // 65536 floats: P [h*256+g]

__device__ int g_pdone = 0;
__device__ int g_bdone = 0;

template<int BF> __device__ __forceinline__ float ld(const void* p, int i) {
  if constexpr (BF) return __bfloat162float(((const __hip_bfloat16*)p)[i]);
  else return ((const float*)p)[i];
}
template<int BF> __device__ __forceinline__ void st(void* p, int i, float v) {
  if constexpr (BF) ((__hip_bfloat16*)p)[i] = __float2bfloat16(v);
  else ((float*)p)[i] = v;
}
__device__ __forceinline__ float b2f(unsigned short u) {
  return __uint_as_float(((unsigned int)u) << 16);
}
// 8 consecutive elements, idx %4==0 (BF path: one 16B uint4 load)
template<int BF> __device__ __forceinline__ void ld8v(const void* p, int i, float* o) {
  if constexpr (BF) {
    uint4 u = *(const uint4*)((const unsigned short*)p + i);
    o[0] = b2f((unsigned short)(u.x & 0xffff)); o[1] = b2f((unsigned short)(u.x >> 16));
    o[2] = b2f((unsigned short)(u.y & 0xffff)); o[3] = b2f((unsigned short)(u.y >> 16));
    o[4] = b2f((unsigned short)(u.z & 0xffff)); o[5] = b2f((unsigned short)(u.z >> 16));
    o[6] = b2f((unsigned short)(u.w & 0xffff)); o[7] = b2f((unsigned short)(u.w >> 16));
  } else {
    float4 a = *(const float4*)((const float*)p + i);
    float4 b = *(const float4*)((const float*)p + i + 4);
    o[0]=a.x; o[1]=a.y; o[2]=a.z; o[3]=a.w; o[4]=b.x; o[5]=b.y; o[6]=b.z; o[7]=b.w;
  }
}

// dtype sniff: view first 256 half-words of state_batch as bf16. fp32 storage
// puts random-exponent garbage in the low halves -> some |v|>1000 w.p. ~1.
__device__ __forceinline__ int blocksniff(const void* sb, int* sh) {
  if (threadIdx.x == 0) *sh = 0;
  __syncthreads();
  float v = fabsf(__bfloat162float(((const __hip_bfloat16*)sb)[threadIdx.x & 255]));
  if (!(v < 1000.0f)) atomicOr(sh, 1);
  __syncthreads();
  return (*sh == 0) ? 1 : 0;
}

// LDS carve (floats) for batch path
#define LXS   0       // 128
#define LVS   128     // 128
#define LW2   256     // 2560 (raw W2, stride 10)
#define LYS   2816    // 16: [0..9]=y, [10]=||v||
#define LRED  2832    // 48: wave partials, reused for F^2 reduce
#define LF1   2880    // 128*12
#define LEL   4416    // 256*12: [0..9]=E, [10]=u
#define LSW2  7488    // 256*12
#define LCL   10560   // 100
#define LCL2  10660   // 100
#define LW2P  10760   // 256*12 padded W2
#define LTOT  13832   // 55.3 KB -> 2 blocks/CU

#define F1ACC(wv, gidx) do { \
    const float* sp_ = &sm[LSW2 + (gidx)*12]; \
    float4 s0_ = *(const float4*)sp_; \
    float4 s1_ = *(const float4*)(sp_+4); \
    float2 s2_ = *(const float2*)(sp_+8); \
    fa[0]+=(wv)*s0_.x; fa[1]+=(wv)*s0_.y; fa[2]+=(wv)*s0_.z; fa[3]+=(wv)*s0_.w; \
    fa[4]+=(wv)*s1_.x; fa[5]+=(wv)*s1_.y; fa[6]+=(wv)*s1_.z; fa[7]+=(wv)*s1_.w; \
    fa[8]+=(wv)*s2_.x; fa[9]+=(wv)*s2_.y; \
  } while (0)

template<int BF>
__device__ void fk_body(const void* tin, const void* sbin, const void* x0in,
                        const void* x1in, const void* W1in, const void* b1in,
                        const void* W2in, void* out, float* ws, float* sm) {
  int bid = blockIdx.x, t = threadIdx.x;
  if (bid >= NB) {
    // ---- helper block: P row (row = bid-NB) ----
    int row = bid - NB;
    float* colh = sm;            // 128
    if (t < 128) colh[t] = ld<BF>(W1in, t * 256 + row);
    __syncthreads();
    float pacc = 0.f;
    for (int d = 0; d < 128; d += 4) {
      float4 c4 = *(const float4*)&colh[d];
      pacc += c4.x * ld<BF>(W1in, (d + 0) * 256 + t);
      pacc += c4.y * ld<BF>(W1in, (d + 1) * 256 + t);
      pacc += c4.z * ld<BF>(W1in, (d + 2) * 256 + t);
      pacc += c4.w * ld<BF>(W1in, (d + 3) * 256 + t);
    }
    // coherent (sc1) store: visible at device coherent point, no dirty L2 line
    __hip_atomic_store(&ws[OP + row * 256 + t], pacc,
                       __ATOMIC_RELAXED, __HIP_MEMORY_SCOPE_AGENT);
    __syncthreads();   // drains vmcnt(0): all 256 coherent stores ack'd
    if (t == 0)        // RELAXED add: plain global_atomic_add, no cache op
      __hip_atomic_fetch_add(&g_pdone, 1, __ATOMIC_RELAXED, __HIP_MEMORY_SCOPE_AGENT);
    return;
  }
  // ---- batch block b ----
  int b = bid;
  int w = t >> 6;
  float tt = ld<BF>(tin, 0);
  float window = 4.f * tt * (1.f - tt);
  if (t < 128) {
    float dev = ld<BF>(sbin, b * 128 + t);
    float v   = ld<BF>(sbin, (NB + b) * 128 + t);
    float x0v = ld<BF>(x0in, b * 128 + t);
    float x1v = ld<BF>(x1in, b * 128 + t);
    sm[LXS + t] = x0v + tt * (x1v - x0v) + window * dev;
    sm[LVS + t] = v;
  }
  for (int i = t; i < 2560; i += 256) sm[LW2 + i] = ld<BF>(W2in, i);
  __syncthreads();                                   // (1)
  // h, w projections (coalesced column reads)
  float hacc = ld<BF>(b1in, t), wacc = 0.f;
  for (int d = 0; d < 128; d += 4) {
    float4 xv = *(const float4*)&sm[LXS + d];
    float4 vv = *(const float4*)&sm[LVS + d];
    float w0 = ld<BF>(W1in, (d + 0) * 256 + t);
    float w1 = ld<BF>(W1in, (d + 1) * 256 + t);
    float w2 = ld<BF>(W1in, (d + 2) * 256 + t);
    float w3 = ld<BF>(W1in, (d + 3) * 256 + t);
    hacc += w0 * xv.x + w1 * xv.y + w2 * xv.z + w3 * xv.w;
    wacc += w0 * vv.x + w1 * vv.y + w2 * vv.z + w3 * vv.w;
  }
  float z  = tanhf(hacc);
  float sg = 1.f - z * z;
  float ug = -2.f * z * sg;
  // own W2 row to regs; sw2 row; padded W2 copy for F^2 phase
  float w2r[10];
  #pragma unroll
  for (int o = 0; o < 10; ++o) w2r[o] = sm[LW2 + t * 10 + o];
  #pragma unroll
  for (int o = 0; o < 10; ++o) sm[LSW2 + t * 12 + o] = sg * w2r[o];
  for (int i = t; i < 3072; i += 256) {
    int r = i / 12, c = i - r * 12;
    sm[LW2P + i] = (c < 10) ? sm[LW2 + r * 10 + c] : 0.f;
  }
  // wave-parallel reductions: y[0..9] and ||v||^2 (slot 10)
  float cval = ug * wacc * wacc;
  float rv[11];
  #pragma unroll
  for (int o = 0; o < 10; ++o) rv[o] = cval * w2r[o];
  rv[10] = (t < 128) ? sm[LVS + t] * sm[LVS + t] : 0.f;
  #pragma unroll
  for (int o = 0; o < 11; ++o) {
    float v = rv[o];
    #pragma unroll
    for (int m = 32; m > 0; m >>= 1) v += __shfl_xor(v, m);
    if ((t & 63) == 0) sm[LRED + w * 12 + o] = v;
  }
  __syncthreads();                                   // (2) sw2/W2P/LRED ready
  if (t < 11) {
    float s = sm[LRED + t] + sm[LRED + 12 + t] + sm[LRED + 24 + t] + sm[LRED + 36 + t];
    if (t < 10) sm[LYS + t] = s;
    else        sm[LYS + 10] = sqrtf(s);             // ||v|| stays in LDS
  }
  // F1[r,o] = sum_g W1[r,g] sw2[g,o]; each thread does half the g-range of one row
  int half = t >> 7, r = t & 127;
  float fa[10];
  #pragma unroll
  for (int o = 0; o < 10; ++o) fa[o] = 0.f;
  {
    const int gbase = half * 128;
    for (int gg = 0; gg < 128; gg += 8) {
      int g = gbase + gg;
      float wv[8];
      ld8v<BF>(W1in, r * 256 + g, wv);   // 16B row gather
      F1ACC(wv[0], g + 0); F1ACC(wv[1], g + 1);
      F1ACC(wv[2], g + 2); F1ACC(wv[3], g + 3);
      F1ACC(wv[4], g + 4); F1ACC(wv[5], g + 5);
      F1ACC(wv[6], g + 6); F1ACC(wv[7], g + 7);
    }
  }
  if (half) {
    #pragma unroll
    for (int o = 0; o < 10; ++o) sm[LF1 + r * 12 + o] = fa[o];
  }
  __syncthreads();                                   // (3) upper partials in LDS
  float aun = 0.f;
  if (!half) {   // t < 128: finalize F1 row, a_un = F1 . y (kept in reg)
    #pragma unroll
    for (int o = 0; o < 10; ++o) {
      float f = fa[o] + sm[LF1 + r * 12 + o];
      sm[LF1 + r * 12 + o] = f;
      aun += f * sm[LYS + o];
    }
  }
  __syncthreads();                                   // (4) F1 final
  // E[t,o] = sum_d W1[d,t] F1[d,o]  (coalesced column reads, broadcast LDS)
  float er[10];
  #pragma unroll
  for (int o = 0; o < 10; ++o) er[o] = 0.f;
  for (int d = 0; d < 128; ++d) {
    float w1v = ld<BF>(W1in, d * 256 + t);
    const float* fp = &sm[LF1 + d * 12];
    float4 a0 = *(const float4*)fp;
    float4 a1 = *(const float4*)(fp + 4);
    float2 a2 = *(const float2*)(fp + 8);
    er[0] += w1v * a0.x; er[1] += w1v * a0.y; er[2] += w1v * a0.z; er[3] += w1v * a0.w;
    er[4] += w1v * a1.x; er[5] += w1v * a1.y; er[6] += w1v * a1.z; er[7] += w1v * a1.w;
    er[8] += w1v * a2.x; er[9] += w1v * a2.y;
  }
  #pragma unroll
  for (int o = 0; o < 10; ++o) sm[LEL + t * 12 + o] = er[o];
  sm[LEL + t * 12 + 10] = ug;                        // u in slot 10
  sm[LEL + t * 12 + 11] = 0.f;
  __syncthreads();                                   // (5) E+u in LDS
  // C[o,p] = sum_g sw2[g,o] E[g,p] -- 200 threads, split g-range
  float cpart = 0.f;
  if (t < 200) {
    int gh = (t >= 100) ? 1 : 0;
    int idx = t - gh * 100;
    int o = idx / 10, p = idx - o * 10;
    const float* sa = &sm[LSW2 + gh * 1536 + o];
    const float* sb = &sm[LEL  + gh * 1536 + p];
    #pragma unroll 4
    for (int g = 0; g < 128; ++g) cpart += sa[g * 12] * sb[g * 12];
    if (gh) sm[LCL2 + idx] = cpart;
  }
  __syncthreads();                                   // (6)
  if (t < 100) sm[LCL + t] = cpart + sm[LCL2 + t];
  __syncthreads();                                   // (7)
  // CW row for this thread's h' -> registers (no global round trip)
  float cwr[10];
  #pragma unroll
  for (int o = 0; o < 10; ++o) {
    float cw = 0.f;
    #pragma unroll
    for (int p = 0; p < 10; ++p) cw += sm[LCL + o * 10 + p] * w2r[p];
    cwr[o] = cw;
  }
  // ---- wait for P: RELAXED spin, no cache-maintenance ops ----
  if (t == 0) {
    while (__hip_atomic_load(&g_pdone, __ATOMIC_RELAXED, __HIP_MEMORY_SCOPE_AGENT) < 256)
      __builtin_amdgcn_s_sleep(2);
  }
  __syncthreads();                                   // (8)
  // ---- F^2 accumulation (P plain loads: fill clean from coherent point) ----
  float acc = 0.f;
  for (int i0 = 0; i0 < 64; i0 += 16) {
    float ph[16];
    #pragma unroll
    for (int j = 0; j < 16; ++j)
      ph[j] = ws[OP + (w * 64 + i0 + j) * 256 + t];   // 16 loads in flight
    #pragma unroll
    for (int j = 0; j < 16; ++j) {
      int h = w * 64 + i0 + j;
      const float* rp = &sm[LEL + h * 12];
      float4 E0 = *(const float4*)rp;
      float4 E1 = *(const float4*)(rp + 4);
      float4 E2 = *(const float4*)(rp + 8);     // E8,E9,u,0
      const float* wp = &sm[LW2P + h * 12];
      float4 W0 = *(const float4*)wp;
      float4 W1v = *(const float4*)(wp + 4);
      float4 W2v = *(const float4*)(wp + 8);    // W8,W9,0,0
      float R = E0.x*w2r[0] + E0.y*w2r[1] + E0.z*w2r[2] + E0.w*w2r[3]
              + E1.x*w2r[4] + E1.y*w2r[5] + E1.z*w2r[6] + E1.w*w2r[7]
              + E2.x*w2r[8] + E2.y*w2r[9];
      float Rt = W0.x*er[0] + W0.y*er[1] + W0.z*er[2] + W0.w*er[3]
               + W1v.x*er[4] + W1v.y*er[5] + W1v.z*er[6] + W1v.w*er[7]
               + W2v.x*er[8] + W2v.y*er[9];
      float Qd = W0.x*cwr[0] + W0.y*cwr[1] + W0.z*cwr[2] + W0.w*cwr[3]
               + W1v.x*cwr[4] + W1v.y*cwr[5] + W1v.z*cwr[6] + W1v.w*cwr[7]
               + W2v.x*cwr[8] + W2v.y*cwr[9];
      acc += E2.z * ph[j] * (ph[j] * Qd + R * Rt);
    }
  }
  acc *= ug;           // u for own column t
  #pragma unroll
  for (int m = 32; m > 0; m >>= 1) acc += __shfl_xor(acc, m);
  if ((t & 63) == 0) sm[LRED + w] = acc;             // LRED reused (old use dead)
  __syncthreads();                                   // (9)
  float F = sqrtf(fmaxf(2.f * (sm[LRED] + sm[LRED+1] + sm[LRED+2] + sm[LRED+3]), 0.f));
  float denom = (F + 1e-6f) * (sm[LYS + 10] + 1e-6f);
  if (t < 128) {
    st<BF>(out, b * 128 + t, ld<BF>(sbin, (NB + b) * 128 + t));   // dev_velocity
    float dev = ld<BF>(sbin, b * 128 + t);
    float val = -aun / denom - 0.1f * dev;
    st<BF>(out, (NB + b) * 128 + t, val);
  }
  __syncthreads();                                   // (10)
  if (t == 0) {
    int old = __hip_atomic_fetch_add(&g_bdone, 1, __ATOMIC_RELAXED, __HIP_MEMORY_SCOPE_AGENT);
    if (old == NB - 1) {   // last batch block: reset flags for next launch
      __hip_atomic_store(&g_pdone, 0, __ATOMIC_RELAXED, __HIP_MEMORY_SCOPE_AGENT);
      __hip_atomic_store(&g_bdone, 0, __ATOMIC_RELAXED, __HIP_MEMORY_SCOPE_AGENT);
    }
  }
}

__global__ __launch_bounds__(256, 2) void FK(const void* tin, const void* sbin,
                                             const void* x0in, const void* x1in,
                                             const void* W1in, const void* b1in,
                                             const void* W2in, void* out, float* ws) {
  __shared__ int sh;
  __shared__ __align__(16) float sm[LTOT];
  int bf = blocksniff(sbin, &sh);
  if (bf) fk_body<1>(tin, sbin, x0in, x1in, W1in, b1in, W2in, out, ws, sm);
  else    fk_body<0>(tin, sbin, x0in, x1in, W1in, b1in, W2in, out, ws, sm);
}

extern "C" void kernel_launch(void* const* d_in, const int* in_sizes, int n_in,
                              void* d_out, int out_size, void* d_ws, size_t ws_size,
                              hipStream_t stream) {
  float* ws = (float*)d_ws;
  const void* tin  = d_in[0];
  const void* sbin = d_in[1];
  const void* x0in = d_in[2];
  const void* x1in = d_in[3];
  const void* W1in = d_in[4];
  const void* b1in = d_in[5];
  const void* W2in = d_in[6];
  // d_in[7] (b2) cancels in every derivative.

  FK<<<dim3(NB + 256), dim3(256), 0, stream>>>(tin, sbin, x0in, x1in, W1in, b1in, W2in, d_out, ws);
}

// Round 5
// 91.619 us; speedup vs baseline: 1.1580x; 1.0864x over previous
//
#include <hip/hip_runtime.h>
#include <hip/hip_bf16.h>

// B=32, D=128, H=256, O=10.
// s = 1-tanh(W1^T x + b1)^2, u = -2 z s, P = W1^T W1 (HxH).
// Rank-10 structure (M = W2 W2^T):
//   sw2[g,o] = s_g W2[g,o]; F1 = W1 sw2 (128x10); E = W1^T F1 (256x10)
//   y_o = sum_h W2[h,o] u_h w_h^2  (w = W1^T v)
//   a_un = W1 (s o (W2 y)) = F1 y
//   C[o,p] = sum_g sw2[g,o] E[g,p] (10x10), CW = C W2^T
//   F^2 = 2 sum u_h u_h' (P^2 o Q + P o R o R^T)   (same band structure as
//     all verified rounds; only fp32 summation order changes here)
//   a_i = -a_un[i]/((F+1e-6)(||v||+1e-6))
// Round-5: batch blocks widened to 512 threads (8 waves = 2/SIMD) -- round-4
// counters showed batch CUs ~78% stalled at 1 wave/SIMD (latency-bound).
// Every heavy phase split across the extra waves; exact sums preserved
// modulo fp32 reorder. Helpers: 128 blocks x 512 thr, 2 P rows each.
// Fence-free relaxed-atomic handoff kept from round 4 (sc1 stores ->
// coherent point; RELAXED flag; plain consumer loads).

#define NB 32
#define OP 0        // ws: P [h*256+g], 65536 floats

__device__ int g_pdone = 0;
__device__ int g_bdone = 0;

template<int BF> __device__ __forceinline__ float ld(const void* p, int i) {
  if constexpr (BF) return __bfloat162float(((const __hip_bfloat16*)p)[i]);
  else return ((const float*)p)[i];
}
template<int BF> __device__ __forceinline__ void st(void* p, int i, float v) {
  if constexpr (BF) ((__hip_bfloat16*)p)[i] = __float2bfloat16(v);
  else ((float*)p)[i] = v;
}
__device__ __forceinline__ float b2f(unsigned short u) {
  return __uint_as_float(((unsigned int)u) << 16);
}
// 8 consecutive elements, idx %8==0 (BF path: one 16B uint4 load)
template<int BF> __device__ __forceinline__ void ld8v(const void* p, int i, float* o) {
  if constexpr (BF) {
    uint4 u = *(const uint4*)((const unsigned short*)p + i);
    o[0] = b2f((unsigned short)(u.x & 0xffff)); o[1] = b2f((unsigned short)(u.x >> 16));
    o[2] = b2f((unsigned short)(u.y & 0xffff)); o[3] = b2f((unsigned short)(u.y >> 16));
    o[4] = b2f((unsigned short)(u.z & 0xffff)); o[5] = b2f((unsigned short)(u.z >> 16));
    o[6] = b2f((unsigned short)(u.w & 0xffff)); o[7] = b2f((unsigned short)(u.w >> 16));
  } else {
    float4 a = *(const float4*)((const float*)p + i);
    float4 b = *(const float4*)((const float*)p + i + 4);
    o[0]=a.x; o[1]=a.y; o[2]=a.z; o[3]=a.w; o[4]=b.x; o[5]=b.y; o[6]=b.z; o[7]=b.w;
  }
}

// dtype sniff: view first 256 half-words of state_batch as bf16. fp32 storage
// puts random-exponent garbage in the low halves -> some |v|>1000 w.p. ~1.
__device__ __forceinline__ int blocksniff(const void* sb, int* sh) {
  if (threadIdx.x == 0) *sh = 0;
  __syncthreads();
  float v = fabsf(__bfloat162float(((const __hip_bfloat16*)sb)[threadIdx.x & 255]));
  if (!(v < 1000.0f)) atomicOr(sh, 1);
  __syncthreads();
  return (*sh == 0) ? 1 : 0;
}

// LDS carve (floats), total 14592 = 58.4 KB (<64KB static cap).
// Region reuse: F1 quarter-partials live in LEL (+0,+1536) and LW2P (+0)
// before those regions' real contents exist; E q=1 partials in LW2P; the
// padded-W2 copy into LW2P is deferred until after the E combine.
#define LXS   0       // 128
#define LVS   128     // 128
#define LW2   256     // 2560 raw W2 (stride 10)
#define LYS   2816    // 16: [0..9]=y, [10]=||v||
#define LRED  2832    // 96: 8 waves * 12 (y phase); [0..7] reused for F^2
#define LHW   2928    // 512: q=1 h/w partials
#define LF1   3440    // 1536: 128*12
#define LEL   4976    // 3072: final [0..9]=E,[10]=u; earlier F1 partials q1/q2
#define LSW2  8048    // 3072
#define LCL   11120   // 100
#define LCQ   11220   // 300: C chunk partials
#define LW2P  11520   // 3072: F1 q3 partial -> E q=1 partial -> padded W2
#define LTOT  14592

#define F1ACC(wv, gidx) do { \
    const float* sp_ = &sm[LSW2 + (gidx)*12]; \
    float4 s0_ = *(const float4*)sp_; \
    float4 s1_ = *(const float4*)(sp_+4); \
    float2 s2_ = *(const float2*)(sp_+8); \
    fa[0]+=(wv)*s0_.x; fa[1]+=(wv)*s0_.y; fa[2]+=(wv)*s0_.z; fa[3]+=(wv)*s0_.w; \
    fa[4]+=(wv)*s1_.x; fa[5]+=(wv)*s1_.y; fa[6]+=(wv)*s1_.z; fa[7]+=(wv)*s1_.w; \
    fa[8]+=(wv)*s2_.x; fa[9]+=(wv)*s2_.y; \
  } while (0)

template<int BF>
__device__ void fk_body(const void* tin, const void* sbin, const void* x0in,
                        const void* x1in, const void* W1in, const void* b1in,
                        const void* W2in, void* out, float* ws, float* sm) {
  int bid = blockIdx.x, t = threadIdx.x;
  if (bid >= NB) {
    // ---- helper block: 2 P rows (row0, row0+1) ----
    int row0 = (bid - NB) * 2;
    float* colh = sm;            // 256: two W1 columns
    if (t < 256) {
      int qq = t >> 7, d = t & 127;
      colh[qq * 128 + d] = ld<BF>(W1in, d * 256 + row0 + qq);
    }
    __syncthreads();
    int q = t >> 8, c = t & 255;
    const float* ch = &colh[q * 128];
    float pacc = 0.f;
    for (int d = 0; d < 128; d += 4) {
      float4 c4 = *(const float4*)&ch[d];
      pacc += c4.x * ld<BF>(W1in, (d + 0) * 256 + c);
      pacc += c4.y * ld<BF>(W1in, (d + 1) * 256 + c);
      pacc += c4.z * ld<BF>(W1in, (d + 2) * 256 + c);
      pacc += c4.w * ld<BF>(W1in, (d + 3) * 256 + c);
    }
    // coherent (sc1) store: visible at device coherent point, no dirty L2 line
    __hip_atomic_store(&ws[OP + (row0 + q) * 256 + c], pacc,
                       __ATOMIC_RELAXED, __HIP_MEMORY_SCOPE_AGENT);
    __syncthreads();   // drains vmcnt(0): all 512 coherent stores ack'd
    if (t == 0)
      __hip_atomic_fetch_add(&g_pdone, 1, __ATOMIC_RELAXED, __HIP_MEMORY_SCOPE_AGENT);
    return;
  }
  // ---- batch block b (512 threads, 8 waves) ----
  int b = bid;
  int t2 = t & 255;          // h / column index
  int q  = t >> 8;           // 0/1 half
  int w  = t >> 6;           // wave 0..7
  int r  = t & 127;          // F1 row
  int qr = t >> 7;           // F1 g-quarter 0..3
  float tt = ld<BF>(tin, 0);
  float window = 4.f * tt * (1.f - tt);
  if (t < 128) {
    float dev = ld<BF>(sbin, b * 128 + t);
    float v   = ld<BF>(sbin, (NB + b) * 128 + t);
    float x0v = ld<BF>(x0in, b * 128 + t);
    float x1v = ld<BF>(x1in, b * 128 + t);
    sm[LXS + t] = x0v + tt * (x1v - x0v) + window * dev;
    sm[LVS + t] = v;
  }
  for (int i = t; i < 2560; i += 512) sm[LW2 + i] = ld<BF>(W2in, i);
  __syncthreads();                                   // (1)
  // h, w projection partials over own d-half (coalesced column reads)
  float hp = q ? 0.f : ld<BF>(b1in, t2), wp = 0.f;
  {
    int d0 = q * 64;
    for (int d = d0; d < d0 + 64; d += 4) {
      float4 xv = *(const float4*)&sm[LXS + d];
      float4 vv = *(const float4*)&sm[LVS + d];
      float w0 = ld<BF>(W1in, (d + 0) * 256 + t2);
      float w1 = ld<BF>(W1in, (d + 1) * 256 + t2);
      float w2 = ld<BF>(W1in, (d + 2) * 256 + t2);
      float w3 = ld<BF>(W1in, (d + 3) * 256 + t2);
      hp += w0 * xv.x + w1 * xv.y + w2 * xv.z + w3 * xv.w;
      wp += w0 * vv.x + w1 * vv.y + w2 * vv.z + w3 * vv.w;
    }
  }
  if (q) { sm[LHW + t2 * 2] = hp; sm[LHW + t2 * 2 + 1] = wp; }
  float w2r[10];
  #pragma unroll
  for (int o = 0; o < 10; ++o) w2r[o] = sm[LW2 + t2 * 10 + o];
  __syncthreads();                                   // (2)
  float ug = 0.f;
  if (!q) {     // combine halves, activation, sw2 row, y/||v|| reduction
    float hacc = hp + sm[LHW + t2 * 2];
    float wacc = wp + sm[LHW + t2 * 2 + 1];
    float z  = tanhf(hacc);
    float sg = 1.f - z * z;
    ug = -2.f * z * sg;
    #pragma unroll
    for (int o = 0; o < 10; ++o) sm[LSW2 + t2 * 12 + o] = sg * w2r[o];
    float cval = ug * wacc * wacc;
    float rv[11];
    #pragma unroll
    for (int o = 0; o < 10; ++o) rv[o] = cval * w2r[o];
    rv[10] = (t < 128) ? sm[LVS + t] * sm[LVS + t] : 0.f;
    #pragma unroll
    for (int o = 0; o < 11; ++o) {
      float v = rv[o];
      #pragma unroll
      for (int m = 32; m > 0; m >>= 1) v += __shfl_xor(v, m);
      if ((t & 63) == 0) sm[LRED + w * 12 + o] = v;
    }
  }
  __syncthreads();                                   // (3)
  if (t < 11) {
    float s = sm[LRED + t] + sm[LRED + 12 + t] + sm[LRED + 24 + t] + sm[LRED + 36 + t];
    if (t < 10) sm[LYS + t] = s;
    else        sm[LYS + 10] = sqrtf(s);
  }
  // F1[r,o] = sum_g W1[r,g] sw2[g,o]; 4-way g-split (64 g per thread)
  float fa[10];
  #pragma unroll
  for (int o = 0; o < 10; ++o) fa[o] = 0.f;
  {
    int gbase = qr * 64;
    for (int gg = 0; gg < 64; gg += 8) {
      int g = gbase + gg;
      float wv[8];
      ld8v<BF>(W1in, r * 256 + g, wv);   // contiguous 16B row gather
      F1ACC(wv[0], g + 0); F1ACC(wv[1], g + 1);
      F1ACC(wv[2], g + 2); F1ACC(wv[3], g + 3);
      F1ACC(wv[4], g + 4); F1ACC(wv[5], g + 5);
      F1ACC(wv[6], g + 6); F1ACC(wv[7], g + 7);
    }
  }
  if (qr == 1) {
    #pragma unroll
    for (int o = 0; o < 10; ++o) sm[LEL + r * 12 + o] = fa[o];
  } else if (qr == 2) {
    #pragma unroll
    for (int o = 0; o < 10; ++o) sm[LEL + 1536 + r * 12 + o] = fa[o];
  } else if (qr == 3) {
    #pragma unroll
    for (int o = 0; o < 10; ++o) sm[LW2P + r * 12 + o] = fa[o];
  }
  __syncthreads();                                   // (4)
  float aun = 0.f;
  if (!qr) {   // t<128: combine quarters, finalize F1 row, a_un = F1 . y
    #pragma unroll
    for (int o = 0; o < 10; ++o) {
      float f = fa[o] + sm[LEL + r * 12 + o] + sm[LEL + 1536 + r * 12 + o]
                      + sm[LW2P + r * 12 + o];
      sm[LF1 + r * 12 + o] = f;
      aun += f * sm[LYS + o];
    }
  }
  __syncthreads();                                   // (5)
  // E[t2,o] = sum_d W1[d,t2] F1[d,o]; 2-way d-split
  float er[10];
  #pragma unroll
  for (int o = 0; o < 10; ++o) er[o] = 0.f;
  {
    int d0 = q * 64;
    for (int d = d0; d < d0 + 64; ++d) {
      float w1v = ld<BF>(W1in, d * 256 + t2);   // coalesced
      const float* fp = &sm[LF1 + d * 12];
      float4 a0 = *(const float4*)fp;
      float4 a1 = *(const float4*)(fp + 4);
      float2 a2 = *(const float2*)(fp + 8);
      er[0] += w1v * a0.x; er[1] += w1v * a0.y; er[2] += w1v * a0.z; er[3] += w1v * a0.w;
      er[4] += w1v * a1.x; er[5] += w1v * a1.y; er[6] += w1v * a1.z; er[7] += w1v * a1.w;
      er[8] += w1v * a2.x; er[9] += w1v * a2.y;
    }
  }
  if (q) {
    #pragma unroll
    for (int o = 0; o < 10; ++o) sm[LW2P + t2 * 12 + o] = er[o];
  }
  __syncthreads();                                   // (6)
  if (!q) {
    #pragma unroll
    for (int o = 0; o < 10; ++o)
      sm[LEL + t2 * 12 + o] = er[o] + sm[LW2P + t2 * 12 + o];
    sm[LEL + t2 * 12 + 10] = ug;
    sm[LEL + t2 * 12 + 11] = 0.f;
  }
  __syncthreads();                                   // (7) E+u final; W2P dead
  // padded W2 copy (deferred; region free now)
  for (int i = t; i < 3072; i += 512) {
    int rr = i / 12, cc = i - rr * 12;
    sm[LW2P + i] = (cc < 10) ? sm[LW2 + rr * 10 + cc] : 0.f;
  }
  // C[o,p] = sum_g sw2[g,o] E[g,p]; 4 g-chunks x 100 threads
  float cpart = 0.f;
  if (t < 400) {
    int chk = t / 100, idx = t - chk * 100;
    int o = idx / 10, p = idx - o * 10;
    const float* sa = &sm[LSW2 + o];
    const float* sb = &sm[LEL + p];
    int g0 = chk * 64;
    #pragma unroll 4
    for (int g = g0; g < g0 + 64; ++g) cpart += sa[g * 12] * sb[g * 12];
    if (chk) sm[LCQ + (chk - 1) * 100 + idx] = cpart;
  }
  __syncthreads();                                   // (8) also covers W2P copy
  if (t < 100)
    sm[LCL + t] = cpart + sm[LCQ + t] + sm[LCQ + 100 + t] + sm[LCQ + 200 + t];
  __syncthreads();                                   // (9)
  // per-column registers for F^2: CW row, full E row, u_c
  float cwr[10];
  #pragma unroll
  for (int o = 0; o < 10; ++o) {
    float cw = 0.f;
    #pragma unroll
    for (int p = 0; p < 10; ++p) cw += sm[LCL + o * 10 + p] * w2r[p];
    cwr[o] = cw;
  }
  float uc;
  {
    const float* ep = &sm[LEL + t2 * 12];
    float4 e0 = *(const float4*)ep;
    float4 e1 = *(const float4*)(ep + 4);
    float4 e2 = *(const float4*)(ep + 8);
    er[0]=e0.x; er[1]=e0.y; er[2]=e0.z; er[3]=e0.w;
    er[4]=e1.x; er[5]=e1.y; er[6]=e1.z; er[7]=e1.w;
    er[8]=e2.x; er[9]=e2.y; uc = e2.z;
  }
  // ---- wait for P: RELAXED spin, no cache-maintenance ops ----
  if (t == 0) {
    while (__hip_atomic_load(&g_pdone, __ATOMIC_RELAXED, __HIP_MEMORY_SCOPE_AGENT) < 128)
      __builtin_amdgcn_s_sleep(2);
  }
  __syncthreads();                                   // (10)
  // ---- F^2: own column c=t2, own 32-row half of the 64-row band ----
  int band = (t2 >> 6) * 64 + q * 32;
  float acc = 0.f;
  for (int i0 = 0; i0 < 32; i0 += 16) {
    float ph[16];
    #pragma unroll
    for (int j = 0; j < 16; ++j)
      ph[j] = ws[OP + (band + i0 + j) * 256 + t2];   // 16 loads in flight
    #pragma unroll
    for (int j = 0; j < 16; ++j) {
      int h = band + i0 + j;
      const float* rp = &sm[LEL + h * 12];
      float4 E0 = *(const float4*)rp;
      float4 E1 = *(const float4*)(rp + 4);
      float4 E2 = *(const float4*)(rp + 8);     // E8,E9,u,0
      const float* wpp = &sm[LW2P + h * 12];
      float4 W0 = *(const float4*)wpp;
      float4 W1v = *(const float4*)(wpp + 4);
      float4 W2v = *(const float4*)(wpp + 8);   // W8,W9,0,0
      float R = E0.x*w2r[0] + E0.y*w2r[1] + E0.z*w2r[2] + E0.w*w2r[3]
              + E1.x*w2r[4] + E1.y*w2r[5] + E1.z*w2r[6] + E1.w*w2r[7]
              + E2.x*w2r[8] + E2.y*w2r[9];
      float Rt = W0.x*er[0] + W0.y*er[1] + W0.z*er[2] + W0.w*er[3]
               + W1v.x*er[4] + W1v.y*er[5] + W1v.z*er[6] + W1v.w*er[7]
               + W2v.x*er[8] + W2v.y*er[9];
      float Qd = W0.x*cwr[0] + W0.y*cwr[1] + W0.z*cwr[2] + W0.w*cwr[3]
               + W1v.x*cwr[4] + W1v.y*cwr[5] + W1v.z*cwr[6] + W1v.w*cwr[7]
               + W2v.x*cwr[8] + W2v.y*cwr[9];
      acc += E2.z * ph[j] * (ph[j] * Qd + R * Rt);
    }
  }
  acc *= uc;
  #pragma unroll
  for (int m = 32; m > 0; m >>= 1) acc += __shfl_xor(acc, m);
  if ((t & 63) == 0) sm[LRED + w] = acc;             // LRED[0..7] (y use dead)
  __syncthreads();                                   // (11)
  float F = sqrtf(fmaxf(2.f * (sm[LRED] + sm[LRED+1] + sm[LRED+2] + sm[LRED+3]
                             + sm[LRED+4] + sm[LRED+5] + sm[LRED+6] + sm[LRED+7]), 0.f));
  float denom = (F + 1e-6f) * (sm[LYS + 10] + 1e-6f);
  if (t < 128) {   // these are !qr threads: they hold aun
    st<BF>(out, b * 128 + t, ld<BF>(sbin, (NB + b) * 128 + t));   // dev_velocity
    float dev = ld<BF>(sbin, b * 128 + t);
    float val = -aun / denom - 0.1f * dev;
    st<BF>(out, (NB + b) * 128 + t, val);
  }
  __syncthreads();                                   // (12)
  if (t == 0) {
    int old = __hip_atomic_fetch_add(&g_bdone, 1, __ATOMIC_RELAXED, __HIP_MEMORY_SCOPE_AGENT);
    if (old == NB - 1) {   // last batch block: reset flags for next launch
      __hip_atomic_store(&g_pdone, 0, __ATOMIC_RELAXED, __HIP_MEMORY_SCOPE_AGENT);
      __hip_atomic_store(&g_bdone, 0, __ATOMIC_RELAXED, __HIP_MEMORY_SCOPE_AGENT);
    }
  }
}

__global__ __launch_bounds__(512) void FK(const void* tin, const void* sbin,
                                          const void* x0in, const void* x1in,
                                          const void* W1in, const void* b1in,
                                          const void* W2in, void* out, float* ws) {
  __shared__ int sh;
  __shared__ __align__(16) float sm[LTOT];
  int bf = blocksniff(sbin, &sh);
  if (bf) fk_body<1>(tin, sbin, x0in, x1in, W1in, b1in, W2in, out, ws, sm);
  else    fk_body<0>(tin, sbin, x0in, x1in, W1in, b1in, W2in, out, ws, sm);
}

extern "C" void kernel_launch(void* const* d_in, const int* in_sizes, int n_in,
                              void* d_out, int out_size, void* d_ws, size_t ws_size,
                              hipStream_t stream) {
  float* ws = (float*)d_ws;
  const void* tin  = d_in[0];
  const void* sbin = d_in[1];
  const void* x0in = d_in[2];
  const void* x1in = d_in[3];
  const void* W1in = d_in[4];
  const void* b1in = d_in[5];
  const void* W2in = d_in[6];
  // d_in[7] (b2) cancels in every derivative.

  FK<<<dim3(NB + 128), dim3(512), 0, stream>>>(tin, sbin, x0in, x1in, W1in, b1in, W2in, d_out, ws);
}